// Round 2
// baseline (695.405 us; speedup 1.0000x reference)
//
#include <hip/hip_runtime.h>

// IndexedConv: out[n,o,l] = bias[o] + sum_{c,k} x[n,c,idx[k,l]] * w[o,c,k]
// N=16, C_IN=32, C_OUT=128, K=7, L=40000.
//
// Strategy: transpose x -> xt[l][n*32+c] (bf16) so each gather (k,l) is one
// contiguous 1KB row; per-l compute is a 16x128x224 GEMM done with
// mfma_f32_16x16x32_bf16 (m = batch-n, one K-step = one k's 32 channels,
// 8 o-tiles of 16). fp32 accumulate, fp32 output.

#define L_TOT 40000
#define NC 512          // N*C_IN = 16*32
#define NBATCH 2500     // L_TOT / 16 (16 l per block-batch)

typedef __bf16 bf16x8 __attribute__((ext_vector_type(8)));
typedef float float4_t __attribute__((ext_vector_type(4)));

// ---------------------------------------------------------------- indices ---
// Probe whether the raw buffer is int64 (odd 32-bit words all 0/-1 since
// values are in [-1,40000)) or int32, then repack to int32.
__global__ void repack_idx(const int* __restrict__ raw, int* __restrict__ idx32) {
    __shared__ unsigned long long votes[4];
    int tid = threadIdx.x;
    int wprobe = raw[2 * tid + 1];            // first 512 ints exist either way
    bool ok = (wprobe == 0) || (wprobe == -1);
    unsigned long long vote = __ballot(ok);
    if ((tid & 63) == 0) votes[tid >> 6] = vote;
    __syncthreads();
    bool is64 = ((votes[0] & votes[1] & votes[2] & votes[3]) == ~0ull);
    int i = blockIdx.x * 256 + tid;
    if (i < 7 * L_TOT) {
        if (is64) idx32[i] = raw[2 * i];      // low word of little-endian int64
        else      idx32[i] = raw[i];
    }
}

// -------------------------------------------------------------- transpose ---
// x (512 rows x 40000 cols fp32) -> xt (40000 rows x 512 cols bf16).
// 64(l) x 32(nc) tiles through LDS; coalesced reads, 16B/lane writes.
__global__ void transpose_cast(const float* __restrict__ x, __bf16* __restrict__ xt) {
    __shared__ float tile[32][66];            // +2 pad: kill bank conflicts
    int l0  = blockIdx.x * 64;
    int nc0 = blockIdx.y * 32;
    int tid = threadIdx.x;
    int lloc = tid & 63, sub = tid >> 6;
#pragma unroll
    for (int i = 0; i < 8; ++i) {
        int nc = i * 4 + sub;
        tile[nc][lloc] = x[(size_t)(nc0 + nc) * L_TOT + l0 + lloc];
    }
    __syncthreads();
    int ll = tid >> 2, g = tid & 3;
    bf16x8 v;
#pragma unroll
    for (int j = 0; j < 8; ++j) v[j] = (__bf16)tile[g * 8 + j][ll];
    *reinterpret_cast<bf16x8*>(xt + (size_t)(l0 + ll) * NC + nc0 + g * 8) = v;
}

// ----------------------------------------------------------------- pack W ---
// wpack[k][t][lane][j] = bf16( w[o=t*16+(lane&15)][c=(lane>>4)*8+j][k] )
// i.e. B-fragment layout (n = lane&15, kdim = quad*8+j) for each (k-step, o-tile).
__global__ void pack_w(const float* __restrict__ w, bf16x8* __restrict__ wp) {
    int gid = blockIdx.x * 256 + threadIdx.x;     // 0..3583
    if (gid >= 7 * 8 * 64) return;
    int k = gid >> 9, r = gid & 511, t = r >> 6, lane = r & 63;
    int col = lane & 15, quad = lane >> 4;
    int o = t * 16 + col;
    bf16x8 v;
#pragma unroll
    for (int j = 0; j < 8; ++j) {
        int c = quad * 8 + j;
        v[j] = (__bf16)w[(o * 32 + c) * 7 + k];
    }
    wp[gid] = v;
}

// ------------------------------------------------------------------- main ---
// Block = 4 waves. Wave w owns l = b*16 + w*4 .. +3 and all 128 o.
// Per wave-batch: 7k x (4 A-gather dwordx4) ; 7k x 8t ds_read_b128 (B) ;
// 7*8*4 = 224 MFMAs ; acc = 4l x 8t x float4 = 128 VGPRs.
__launch_bounds__(256, 2)
__global__ void indexed_conv_main(const __bf16* __restrict__ xt,
                                  const bf16x8* __restrict__ wp,
                                  const float* __restrict__ bias,
                                  const int* __restrict__ idx,
                                  float* __restrict__ out) {
    __shared__ bf16x8 ldsW[3584];                 // 57,344 B
    int tid = threadIdx.x;
    for (int i = tid; i < 3584; i += 256) ldsW[i] = wp[i];

    int wave = tid >> 6, lane = tid & 63;
    int col = lane & 15, quad = lane >> 4;
    float bv[8];
#pragma unroll
    for (int t = 0; t < 8; ++t) bv[t] = bias[t * 16 + col];
    __syncthreads();

    // A-fragment lane offset inside a 512-elem xt row, in bf16x8 units:
    // element (m*32 + quad*8) with m = lane&15  ->  /8 = col*4 + quad
    int aoff = col * 4 + quad;

    for (int b = blockIdx.x; b < NBATCH; b += gridDim.x) {
        int l0 = b * 16 + wave * 4;

        float4_t acc[4][8];
#pragma unroll
        for (int li = 0; li < 4; ++li)
#pragma unroll
            for (int t = 0; t < 8; ++t)
                acc[li][t] = (float4_t){bv[t], bv[t], bv[t], bv[t]};

#pragma unroll 1
        for (int k = 0; k < 7; ++k) {
            bf16x8 a[4];
#pragma unroll
            for (int li = 0; li < 4; ++li) {
                int iv = idx[k * L_TOT + l0 + li];   // wave-uniform
                if (iv >= 0) {
                    const bf16x8* row =
                        reinterpret_cast<const bf16x8*>(xt + (size_t)iv * NC);
                    a[li] = row[aoff];
                } else {
#pragma unroll
                    for (int j = 0; j < 8; ++j) a[li][j] = (__bf16)0.0f;
                }
            }
#pragma unroll
            for (int t = 0; t < 8; ++t) {
                bf16x8 bw = ldsW[(k * 8 + t) * 64 + lane];
#pragma unroll
                for (int li = 0; li < 4; ++li)
                    acc[li][t] = __builtin_amdgcn_mfma_f32_16x16x32_bf16(
                        a[li], bw, acc[li][t], 0, 0, 0);
            }
        }

        // Epilogue: C/D layout col=lane&15 (o), row=quad*4+reg (n);
        // li (4 consecutive l) vectorizes into one dwordx4 store.
#pragma unroll
        for (int t = 0; t < 8; ++t) {
            int o = t * 16 + col;
#pragma unroll
            for (int reg = 0; reg < 4; ++reg) {
                int n = quad * 4 + reg;
                float4_t v = {acc[0][t][reg], acc[1][t][reg],
                              acc[2][t][reg], acc[3][t][reg]};
                *reinterpret_cast<float4_t*>(
                    out + (size_t)(n * 128 + o) * L_TOT + l0) = v;
            }
        }
    }
}

// ----------------------------------------------------------------- launch ---
extern "C" void kernel_launch(void* const* d_in, const int* in_sizes, int n_in,
                              void* d_out, int out_size, void* d_ws, size_t ws_size,
                              hipStream_t stream) {
    const float* x    = (const float*)d_in[0];
    const float* w    = (const float*)d_in[1];
    const float* bias = (const float*)d_in[2];
    const int*   raw  = (const int*)d_in[3];
    float* out = (float*)d_out;

    char* ws = (char*)d_ws;
    __bf16* xt   = (__bf16*)(ws);                    // 40000*512*2 = 40,960,000 B
    bf16x8* wpck = (bf16x8*)(ws + 40960000);         //               57,344 B
    int*    idx32 = (int*)(ws + 41017344);           //            1,120,000 B

    repack_idx<<<(7 * L_TOT + 255) / 256, 256, 0, stream>>>(raw, idx32);
    transpose_cast<<<dim3(L_TOT / 64, NC / 32), 256, 0, stream>>>(x, xt);
    pack_w<<<14, 256, 0, stream>>>(w, wpck);
    indexed_conv_main<<<512, 256, 0, stream>>>(xt, wpck, bias, idx32, out);
}

// Round 3
// 532.014 us; speedup vs baseline: 1.3071x; 1.3071x over previous
//
#include <hip/hip_runtime.h>

// IndexedConv: out[n,o,l] = bias[o] + sum_{c,k} x[n,c,idx[k,l]] * w[o,c,k]
// N=16, C_IN=32, C_OUT=128, K=7, L=40000.
//
// xt[l][n*32+c] bf16 -> each gather (k,l) is one contiguous 1KB row; per-l
// compute is 16x128x224 GEMM via mfma_f32_16x16x32_bf16. fp32 acc/output.
//
// R2: full k-unroll + idx prefetch (one b ahead) + branch-free gathers
//     (predicated zero) + raw s_barrier before epilogue to merge the 4 waves'
//     16B partial-line stores in L2 (R1 showed 1.98x write amplification).

#define L_TOT 40000
#define NC 512          // N*C_IN = 16*32
#define NBATCH 2500     // L_TOT / 16 (16 l per block-batch)

typedef __bf16 bf16x8 __attribute__((ext_vector_type(8)));
typedef float float4_t __attribute__((ext_vector_type(4)));
typedef int int4v __attribute__((ext_vector_type(4)));

// ---------------------------------------------------------------- indices ---
__global__ void repack_idx(const int* __restrict__ raw, int* __restrict__ idx32) {
    __shared__ unsigned long long votes[4];
    int tid = threadIdx.x;
    int wprobe = raw[2 * tid + 1];            // first 512 ints exist either way
    bool ok = (wprobe == 0) || (wprobe == -1);
    unsigned long long vote = __ballot(ok);
    if ((tid & 63) == 0) votes[tid >> 6] = vote;
    __syncthreads();
    bool is64 = ((votes[0] & votes[1] & votes[2] & votes[3]) == ~0ull);
    int i = blockIdx.x * 256 + tid;
    if (i < 7 * L_TOT) {
        if (is64) idx32[i] = raw[2 * i];      // low word of little-endian int64
        else      idx32[i] = raw[i];
    }
}

// -------------------------------------------------------------- transpose ---
__global__ void transpose_cast(const float* __restrict__ x, __bf16* __restrict__ xt) {
    __shared__ float tile[32][66];
    int l0  = blockIdx.x * 64;
    int nc0 = blockIdx.y * 32;
    int tid = threadIdx.x;
    int lloc = tid & 63, sub = tid >> 6;
#pragma unroll
    for (int i = 0; i < 8; ++i) {
        int nc = i * 4 + sub;
        tile[nc][lloc] = x[(size_t)(nc0 + nc) * L_TOT + l0 + lloc];
    }
    __syncthreads();
    int ll = tid >> 2, g = tid & 3;
    bf16x8 v;
#pragma unroll
    for (int j = 0; j < 8; ++j) v[j] = (__bf16)tile[g * 8 + j][ll];
    *reinterpret_cast<bf16x8*>(xt + (size_t)(l0 + ll) * NC + nc0 + g * 8) = v;
}

// ----------------------------------------------------------------- pack W ---
// B-fragment layout: o = lane&15, c = (lane>>4)*8 + j, one frag per (k, o-tile).
__global__ void pack_w(const float* __restrict__ w, bf16x8* __restrict__ wp) {
    int gid = blockIdx.x * 256 + threadIdx.x;     // 0..3583
    if (gid >= 7 * 8 * 64) return;
    int k = gid >> 9, r = gid & 511, t = r >> 6, lane = r & 63;
    int col = lane & 15, quad = lane >> 4;
    int o = t * 16 + col;
    bf16x8 v;
#pragma unroll
    for (int j = 0; j < 8; ++j) {
        int c = quad * 8 + j;
        v[j] = (__bf16)w[(o * 32 + c) * 7 + k];
    }
    wp[gid] = v;
}

// ------------------------------------------------------------------- main ---
__launch_bounds__(256, 2)
__global__ void indexed_conv_main(const __bf16* __restrict__ xt,
                                  const bf16x8* __restrict__ wp,
                                  const float* __restrict__ bias,
                                  const int* __restrict__ idx,
                                  float* __restrict__ out) {
    __shared__ bf16x8 ldsW[3584];                 // 57,344 B
    int tid = threadIdx.x;
    for (int i = tid; i < 3584; i += 256) ldsW[i] = wp[i];

    int wave = tid >> 6, lane = tid & 63;
    int col = lane & 15, quad = lane >> 4;
    float bv[8];
#pragma unroll
    for (int t = 0; t < 8; ++t) bv[t] = bias[t * 16 + col];

    bf16x8 zero;
#pragma unroll
    for (int j = 0; j < 8; ++j) zero[j] = (__bf16)0.0f;

    __syncthreads();

    // A-fragment lane offset within a 512-elem xt row, in 16B units:
    // element (m*32 + quad*8), m = lane&15  ->  /8 = col*4 + quad
    int aoff = col * 4 + quad;

    int b = blockIdx.x;
    int4v idxc[7];
    if (b < NBATCH) {
        int l0 = b * 16 + wave * 4;
#pragma unroll
        for (int k = 0; k < 7; ++k)
            idxc[k] = *reinterpret_cast<const int4v*>(idx + k * L_TOT + l0);
    }

    for (; b < NBATCH; b += gridDim.x) {
        int l0 = b * 16 + wave * 4;

        // Prefetch next iteration's indices now (consumed one full b later).
        int bn = b + gridDim.x;
        int4v idxn[7];
        if (bn < NBATCH) {
            int l0n = bn * 16 + wave * 4;
#pragma unroll
            for (int k = 0; k < 7; ++k)
                idxn[k] = *reinterpret_cast<const int4v*>(idx + k * L_TOT + l0n);
        }

        float4_t acc[4][8];
#pragma unroll
        for (int li = 0; li < 4; ++li)
#pragma unroll
            for (int t = 0; t < 8; ++t)
                acc[li][t] = (float4_t){bv[t], bv[t], bv[t], bv[t]};

#pragma unroll
        for (int k = 0; k < 7; ++k) {
            bf16x8 a[4];
#pragma unroll
            for (int li = 0; li < 4; ++li) {
                int v = idxc[k][li];
                int s = v < 0 ? 0 : v;                 // safe row
                const bf16x8* row =
                    reinterpret_cast<const bf16x8*>(xt + (size_t)s * NC);
                bf16x8 g = row[aoff];                  // unconditional issue
                a[li] = (v < 0) ? zero : g;            // cndmask, no branch
            }
#pragma unroll
            for (int t = 0; t < 8; ++t) {
                bf16x8 bw = ldsW[(k * 8 + t) * 64 + lane];
#pragma unroll
                for (int li = 0; li < 4; ++li)
                    acc[li][t] = __builtin_amdgcn_mfma_f32_16x16x32_bf16(
                        a[li], bw, acc[li][t], 0, 0, 0);
            }
        }

        // Align the block's 4 waves so their 16B stores into shared 64B lines
        // land close in time and merge in L2 (R1: WRITE_SIZE was 1.98x ideal).
        // Raw s_barrier: no vmcnt drain, prefetched idxn loads stay in flight.
        __builtin_amdgcn_s_barrier();

#pragma unroll
        for (int t = 0; t < 8; ++t) {
            int o = t * 16 + col;
#pragma unroll
            for (int reg = 0; reg < 4; ++reg) {
                int n = quad * 4 + reg;
                float4_t v = {acc[0][t][reg], acc[1][t][reg],
                              acc[2][t][reg], acc[3][t][reg]};
                *reinterpret_cast<float4_t*>(
                    out + (size_t)(n * 128 + o) * L_TOT + l0) = v;
            }
        }

#pragma unroll
        for (int k = 0; k < 7; ++k) idxc[k] = idxn[k];
    }
}

// ----------------------------------------------------------------- launch ---
extern "C" void kernel_launch(void* const* d_in, const int* in_sizes, int n_in,
                              void* d_out, int out_size, void* d_ws, size_t ws_size,
                              hipStream_t stream) {
    const float* x    = (const float*)d_in[0];
    const float* w    = (const float*)d_in[1];
    const float* bias = (const float*)d_in[2];
    const int*   raw  = (const int*)d_in[3];
    float* out = (float*)d_out;

    char* ws = (char*)d_ws;
    __bf16* xt   = (__bf16*)(ws);                    // 40000*512*2 = 40,960,000 B
    bf16x8* wpck = (bf16x8*)(ws + 40960000);         //               57,344 B
    int*    idx32 = (int*)(ws + 41017344);           //            1,120,000 B

    repack_idx<<<(7 * L_TOT + 255) / 256, 256, 0, stream>>>(raw, idx32);
    transpose_cast<<<dim3(L_TOT / 64, NC / 32), 256, 0, stream>>>(x, xt);
    pack_w<<<14, 256, 0, stream>>>(w, wpck);
    indexed_conv_main<<<512, 256, 0, stream>>>(xt, wpck, bias, idx32, out);
}